// Round 7
// baseline (447.327 us; speedup 1.0000x reference)
//
#include <hip/hip_runtime.h>
#include <math.h>

typedef __attribute__((ext_vector_type(2))) float f32x2;

#define MAX_DELAY 128
#define INPUT 64
#define HIDDEN 128
#define HALF 64
#define OUT 64
#define BATCH 32
#define T 128
#define OUT_LEN 64
#define NTHR 512

static __device__ __forceinline__ f32x2 splat2(float v) { f32x2 r; r.x = v; r.y = v; return r; }

template <int CTRL>
static __device__ __forceinline__ float dpp_movf(float v) {
    return __int_as_float(__builtin_amdgcn_update_dpp(
        0, __float_as_int(v), CTRL, 0xF, 0xF, true));
}
#define DPP_XOR1 0xB1  // quad_perm [1,0,3,2]
#define DPP_XOR2 0x4E  // quad_perm [2,3,0,1]

// Lockstep wave specialization, 1 block (8 waves) per batch element.
//  net waves   (tid   0..255, waves 0-3): serial chain msg->h1->tau/mem->head,
//              plus out-proj (one step behind) and x staging. All weights in
//              registers (VGPR+AGPR unified file).
//  blend waves (tid 256..511, waves 4-7): full 128-deep delay buffer in regs
//              (2 thr/channel x 64 delays), applying step i-1's blend during
//              step i, spread over segs A-C. Pure register ALU -> always
//              issuable while the sibling net wave waits on LDS/barriers.
// Both branches execute exactly 4 __syncthreads per iteration (same count,
// same loop bound) -> deadlock-free. Data handoffs are >=1 barrier apart.
__global__ __launch_bounds__(NTHR, 2)
void delayrnn_kernel(
    const float* __restrict__ x,        // (B, T, INPUT)
    const int*   __restrict__ lengths,  // (B)
    const float* __restrict__ Wm,       // (INPUT+HIDDEN, HIDDEN)
    const float* __restrict__ bm,       // (HIDDEN)
    const float* __restrict__ W1,       // (HIDDEN, HALF)
    const float* __restrict__ b1,       // (HALF)
    const float* __restrict__ W2,       // (HALF, 2*HIDDEN)
    const float* __restrict__ b2,       // (2*HIDDEN)
    const float* __restrict__ Wo,       // (HIDDEN, OUT)
    const float* __restrict__ bo,       // (OUT)
    float* __restrict__ out)            // (B, OUT_LEN, OUT)
{
    const int b   = blockIdx.x;
    const int tid = threadIdx.x;
    const int len = lengths[b];
    const int total = len + OUT_LEN;

    __shared__ float s_x[T * INPUT];        // 32 KB staged input
    __shared__ float s_v[INPUT + HIDDEN];   // [x_t | heads]
    __shared__ float s_msg[2][HIDDEN];      // parity double-buffered
    __shared__ float s_h1[HALF];
    __shared__ float s_tau[HIDDEN];
    __shared__ float s_mem[HIDDEN];
    __shared__ float s_y1[HIDDEN];          // post-blend delay-1 values

    for (int idx = tid; idx < T * INPUT; idx += NTHR)
        s_x[idx] = x[b * T * INPUT + idx];
    if (tid < INPUT) s_v[tid] = (0 < len) ? x[b * T * INPUT + tid] : 0.f;
    if (tid >= INPUT && tid < INPUT + HIDDEN) s_v[tid] = 0.f;   // heads = 0
    if (tid < HIDDEN) { s_y1[tid] = 0.f; s_tau[tid] = 0.f; s_mem[tid] = 0.f; }
    __syncthreads();

    if (tid < 256) {
        // ============================ NET ============================
        const int ch = tid >> 1, r   = tid & 1;   // msg: 2 thr/out, K=96
        const int k1 = tid >> 2, r4  = tid & 3;   // h1:  4 thr/out, K=32
        const int cl = tid;                       // tau/mem: 1 out/thr, K=64
        const int oc = tid >> 2, orr = tid & 3;   // out: 4 thr/out, K=32

        f32x2 wm[48];
#pragma unroll
        for (int j = 0; j < 48; ++j) {
            wm[j].x = Wm[(r * 96 + 2 * j)     * HIDDEN + ch];
            wm[j].y = Wm[(r * 96 + 2 * j + 1) * HIDDEN + ch];
        }
        f32x2 w1[16];
#pragma unroll
        for (int j = 0; j < 16; ++j) {
            w1[j].x = W1[(r4 * 32 + 2 * j)     * HALF + k1];
            w1[j].y = W1[(r4 * 32 + 2 * j + 1) * HALF + k1];
        }
        f32x2 w2[32];
#pragma unroll
        for (int j = 0; j < 32; ++j) {
            w2[j].x = W2[(2 * j)     * (2 * HIDDEN) + cl];
            w2[j].y = W2[(2 * j + 1) * (2 * HIDDEN) + cl];
        }
        f32x2 wo[16];
#pragma unroll
        for (int j = 0; j < 16; ++j) {
            wo[j].x = Wo[(orr * 32 + 2 * j)     * OUT + oc];
            wo[j].y = Wo[(orr * 32 + 2 * j + 1) * OUT + oc];
        }
        const float bm_r = bm[ch];
        const float b1_r = b1[k1];
        const float b2_r = b2[cl];
        const float bo_r = bo[oc];

        float tau_own = 0.f;   // cl<128: this thread's tau[cl]

        for (int i = 0; i < total; ++i) {
            const int par = i & 1;
            // ---- seg A: msg[ch] = tanh(v . Wm + bm) ----
            const f32x2* v2 = (const f32x2*)(s_v + r * 96);
            f32x2 a0 = splat2(0.f), a1 = splat2(0.f), a2 = splat2(0.f), a3 = splat2(0.f);
#pragma unroll
            for (int j = 0; j < 48; j += 4) {
                a0 += wm[j] * v2[j];         a1 += wm[j + 1] * v2[j + 1];
                a2 += wm[j + 2] * v2[j + 2]; a3 += wm[j + 3] * v2[j + 3];
            }
            f32x2 aa = (a0 + a1) + (a2 + a3);
            float p = aa.x + aa.y;
            p += dpp_movf<DPP_XOR1>(p);                 // pair reduce
            const float z   = p + bm_r;
            const float e2  = __expf(2.f * z);
            const float msg = 1.f - 2.f * __builtin_amdgcn_rcpf(e2 + 1.f);
            if (r == 0) s_msg[par][ch] = msg;
            __syncthreads();                            // #1

            // ---- seg B: h1 + out-proj of step i-1 ----
            const f32x2* m2 = (const f32x2*)(s_msg[par] + r4 * 32);
            f32x2 c0 = splat2(0.f), c1 = splat2(0.f);
#pragma unroll
            for (int j = 0; j < 16; j += 2) { c0 += w1[j] * m2[j]; c1 += w1[j + 1] * m2[j + 1]; }
            f32x2 cc = c0 + c1;
            float p1 = cc.x + cc.y;
            p1 += dpp_movf<DPP_XOR1>(p1);
            p1 += dpp_movf<DPP_XOR2>(p1);
            if (r4 == 0) s_h1[k1] = fmaxf(p1 + b1_r, 0.f);
            if (i - 1 >= len) {                         // decode output (lagged)
                const f32x2* mo = (const f32x2*)(s_msg[par ^ 1] + orr * 32);
                f32x2 o0 = splat2(0.f), o1 = splat2(0.f);
#pragma unroll
                for (int j = 0; j < 16; j += 2) { o0 += wo[j] * mo[j]; o1 += wo[j + 1] * mo[j + 1]; }
                f32x2 oo = o0 + o1;
                float po = oo.x + oo.y;
                po += dpp_movf<DPP_XOR1>(po);
                po += dpp_movf<DPP_XOR2>(po);
                if (orr == 0) out[(b * OUT_LEN + (i - 1 - len)) * OUT + oc] = po + bo_r;
            }
            __syncthreads();                            // #2

            // ---- seg C: tau/mem (K=64, one output per thread) ----
            const f32x2* h2 = (const f32x2*)s_h1;
            f32x2 t0 = splat2(0.f), t1 = splat2(0.f);
#pragma unroll
            for (int j = 0; j < 32; j += 2) { t0 += w2[j] * h2[j]; t1 += w2[j + 1] * h2[j + 1]; }
            f32x2 tt = t0 + t1;
            const float pt = tt.x + tt.y;
            const float g = __builtin_amdgcn_rcpf(1.f + __expf(-(pt + b2_r)));
            if (cl < HIDDEN) { s_tau[cl] = g; tau_own = g; }
            else             s_mem[cl - HIDDEN] = g;
            __syncthreads();                            // #3

            // ---- seg D: head blend + publish; stage next x ----
            if (cl < HIDDEN) {
                const float msg_i = s_msg[par][cl];
                const float mem_i = s_mem[cl];
                const float nb    = s_y1[cl];           // post-(i-1) delay-1
                const float a     = fabsf(tau_own);
                const float iw    = a * (a * mem_i - 2.f * mem_i) + mem_i;
                s_v[INPUT + cl] = nb + iw * (msg_i - nb);
            }
            if (tid < INPUT) {
                const int nx = i + 1;
                s_v[tid] = (nx < len) ? s_x[nx * INPUT + tid] : 0.f;
            }
            __syncthreads();                            // #4
        }

        // epilogue: out for step total-1 (always a decode step)
        {
            const int par = (total - 1) & 1;
            const f32x2* mo = (const f32x2*)(s_msg[par] + orr * 32);
            f32x2 o0 = splat2(0.f), o1 = splat2(0.f);
#pragma unroll
            for (int j = 0; j < 16; j += 2) { o0 += wo[j] * mo[j]; o1 += wo[j + 1] * mo[j + 1]; }
            f32x2 oo = o0 + o1;
            float po = oo.x + oo.y;
            po += dpp_movf<DPP_XOR1>(po);
            po += dpp_movf<DPP_XOR2>(po);
            if (orr == 0) out[(b * OUT_LEN + (OUT_LEN - 1)) * OUT + oc] = po + bo_r;
        }
    } else {
        // =========================== BLEND ===========================
        const int v  = tid - 256;
        const int ch = v >> 1, pp = v & 1;   // channel ch; delays pp*64+k
        float buf[64];
#pragma unroll
        for (int d = 0; d < 64; ++d) buf[d] = 0.f;

        const float ivb = pp ? 0.5f : 0.f;
        float msg_p = 0.f, tau_p = 0.f, mem_p = 0.f;   // params of step i-1

        for (int i = 0; i < total; ++i) {
            const int par = i & 1;
            // sibling's pre-shift head (delay 64 for pp=0), read before overwrite
            const float old64 = dpp_movf<DPP_XOR1>(buf[0]);
            const float taup  = tau_p - ivb;
            const f32x2 tau2  = splat2(taup);
            const f32x2 mem2  = splat2(mem_p);
            const f32x2 m2m   = splat2(-2.f * mem_p);
            const f32x2 msg2  = splat2(msg_p);
            const float tail  = pp ? 0.f : old64;

#define BLEND_PAIR(M)                                                        \
            {                                                                \
                const int k = 2 * (M);                                       \
                f32x2 nb;                                                    \
                nb.x = buf[k + 1];                                           \
                nb.y = ((M) < 31) ? buf[k + 2] : tail;                       \
                f32x2 t;                                                     \
                t.x = tau2.x - (float)k       * (1.f / MAX_DELAY);           \
                t.y = tau2.y - (float)(k + 1) * (1.f / MAX_DELAY);           \
                f32x2 a  = __builtin_elementwise_max(t, -t);                 \
                f32x2 f1 = a * mem2 + m2m;                                   \
                f32x2 iw = a * f1 + mem2;                                    \
                f32x2 nv = iw * (msg2 - nb) + nb;                            \
                buf[k] = nv.x; buf[k + 1] = nv.y;                            \
            }

            // chunk 1 (seg A): pairs 0..10; publish post-blend delay-1
#pragma unroll
            for (int m = 0; m <= 10; ++m) BLEND_PAIR(m)
            if (pp == 0) s_y1[ch] = buf[1];
            __syncthreads();                            // #1

            // chunk 2 (seg B): pairs 11..21
#pragma unroll
            for (int m = 11; m <= 21; ++m) BLEND_PAIR(m)
            __syncthreads();                            // #2

            // chunk 3 (seg C): pairs 22..31 (incl. cross-thread tail)
#pragma unroll
            for (int m = 22; m <= 31; ++m) BLEND_PAIR(m)
            __syncthreads();                            // #3

            // seg D: load step-i params for next iteration's blend
            msg_p = s_msg[par][ch];
            tau_p = s_tau[ch];
            mem_p = s_mem[ch];
            __syncthreads();                            // #4
#undef BLEND_PAIR
        }
    }
}

extern "C" void kernel_launch(void* const* d_in, const int* in_sizes, int n_in,
                              void* d_out, int out_size, void* d_ws, size_t ws_size,
                              hipStream_t stream) {
    const float* x       = (const float*)d_in[0];
    const int*   lengths = (const int*)  d_in[1];
    // d_in[2] = out_lengths scalar (compile-time 64)
    const float* Wm = (const float*)d_in[3];
    const float* bm = (const float*)d_in[4];
    const float* W1 = (const float*)d_in[5];
    const float* b1 = (const float*)d_in[6];
    const float* W2 = (const float*)d_in[7];
    const float* b2 = (const float*)d_in[8];
    const float* Wo = (const float*)d_in[9];
    const float* bo = (const float*)d_in[10];
    float* out = (float*)d_out;

    delayrnn_kernel<<<BATCH, NTHR, 0, stream>>>(
        x, lengths, Wm, bm, W1, b1, W2, b2, Wo, bo, out);
}